// Round 14
// baseline (268.384 us; speedup 1.0000x reference)
//
#include <hip/hip_runtime.h>
#include <hip/hip_fp16.h>

typedef float v2f __attribute__((ext_vector_type(2)));

#define IMG_H 512
#define IMG_W 512
#define NVIEW 768
#define NDCT 736
#define NT 725
#define PAD 2
#define PW (IMG_W + 2 * PAD)   // 516
#define PH (IMG_H + 2 * PAD)   // 516
#define TROWS 36               // minor axis 32 + 4 margin
#define TCOLS 132              // major axis 128 + 4 margin
#define LSTR 160               // LDS row stride in 4B entries (0 mod 32)
#define VCHUNK 16

// Repack [2,H,W] float -> zero-padded [PH,PW] __half2 (ch0,ch1), plus
// transposed copy.
__global__ void repack_kernel(const float* __restrict__ in,
                              __half2* __restrict__ packed,
                              __half2* __restrict__ packedT) {
    int i = blockIdx.x * blockDim.x + threadIdx.x;
    if (i < PH * PW) {
        int py = i / PW;
        int px = i - py * PW;
        int y = py - PAD;
        int x = px - PAD;
        float2 v = make_float2(0.0f, 0.0f);
        if ((unsigned)x < (unsigned)IMG_W && (unsigned)y < (unsigned)IMG_H) {
            v = make_float2(in[y * IMG_W + x], in[IMG_H * IMG_W + y * IMG_W + x]);
        }
        __half2 h = __floats2half2_rn(v.x, v.y);
        packed[py * PW + px] = h;      // [y][x]
        packedT[px * PW + py] = h;     // [x][y]
    }
}

// Bilinear sample at pos=(col,row); texels are __half2 (both channels);
// lerp in packed f16, accumulate in f32.
__device__ __forceinline__ void lsamp(const __half2* __restrict__ lds, v2f pos, v2f& acc) {
    float fx = floorf(pos.x);
    float fy = floorf(pos.y);
    int xi = (int)fx;
    int yi = (int)fy;
    float wx = pos.x - fx;
    float wy = pos.y - fy;
    int idx = yi * LSTR + xi;
    __half2 v00 = lds[idx];
    __half2 v01 = lds[idx + 1];
    __half2 v10 = lds[idx + LSTR];
    __half2 v11 = lds[idx + LSTR + 1];
    __half2 hwx = __float2half2_rn(wx);
    __half2 hwy = __float2half2_rn(wy);
    __half2 top = __hfma2(hwx, __hsub2(v01, v00), v00);
    __half2 bot = __hfma2(hwx, __hsub2(v11, v10), v10);
    __half2 smp = __hfma2(hwy, __hsub2(bot, top), top);
    acc += (v2f){__low2float(smp), __high2float(smp)};
}

__global__ __launch_bounds__(512, 8) void radon_tile_kernel(const __half2* __restrict__ packed,
                                                            const __half2* __restrict__ packedT,
                                                            float* __restrict__ out) {
    __shared__ __half2 lds[TROWS * LSTR];   // 23040 B

    const int tid = threadIdx.x;
    const int bx = blockIdx.x;
    const int by = blockIdx.y;
    const bool classA = (by < 12) || (by >= 36);   // |cos| >= |sin|

    int x0, y0;
    float xlo, xhi, ylo, yhi;
    if (classA) {                 // tile 128 wide (x) x 32 tall (y)
        int tx = bx & 3, ty = bx >> 2;         // 4 x 16
        x0 = tx * 128; y0 = ty * 32;
        xlo = (tx == 0) ? -1.25f : (float)x0;
        xhi = (tx == 3) ? 512.25f : (float)(x0 + 128);
        ylo = (ty == 0) ? -1.25f : (float)y0;
        yhi = (ty == 15) ? 512.25f : (float)(y0 + 32);
    } else {                      // tile 32 wide (x) x 128 tall (y)
        int tx = bx & 15, ty = bx >> 4;        // 16 x 4
        x0 = tx * 32; y0 = ty * 128;
        xlo = (tx == 0) ? -1.25f : (float)x0;
        xhi = (tx == 15) ? 512.25f : (float)(x0 + 32);
        ylo = (ty == 0) ? -1.25f : (float)y0;
        yhi = (ty == 3) ? 512.25f : (float)(y0 + 128);
    }

    // Stage 36x132 texels; class B reads the transposed copy (coalesced).
    {
        const __half2* src = classA ? packed : packedT;
        const int rbase = classA ? y0 : x0;
        const int cbase = classA ? x0 : y0;
        for (int i = tid; i < TROWS * TCOLS; i += 512) {
            int r = i / TCOLS;
            int cc = i - r * TCOLS;
            lds[r * LSTR + cc] = src[(rbase + r) * PW + (cbase + cc)];
        }
    }
    __syncthreads();

    const int wid = tid >> 6;
    const int lane = tid & 63;
    const float cx = 255.5f;        // == cy
    const float doff = 367.5f;      // (NDCT-1)/2
    const float T0 = -362.0f;       // -(NT-1)/2
    const float x0f = (float)x0, y0f = (float)y0;
    const int vbase = by * VCHUNK;

    for (int task = wid; task < 2 * VCHUNK; task += 8) {
        const int view = vbase + (task >> 1);
        const int half = task & 1;
        const float theta = (float)view * (float)(3.14159265358979323846 / (double)NVIEW);
        float sn, c;
        sincosf(theta, &sn, &c);

        // det range touching this tile: s = c*(x-cx) + sn*(y-cy).
        float xa = c * (xlo - cx), xb = c * (xhi - cx);
        float ya = sn * (ylo - cx), yb = sn * (yhi - cx);
        float smin = fminf(xa, xb) + fminf(ya, yb) - 1.0f;
        float smax = fmaxf(xa, xb) + fmaxf(ya, yb) + 1.0f;
        int detlo = max(0, (int)ceilf(smin + doff));
        int dethi = min(NDCT - 1, (int)floorf(smax + doff));

        if (detlo + (half << 6) > dethi) continue;

        auto do_ray = [&](int det) {
            bool active = (det <= dethi);
            float s = (float)det - doff;
            float sx = fmaf(s, c, cx);      // x(t) = sx - t*sn
            float sy = fmaf(s, sn, cx);     // y(t) = sy + t*c

            // Half-open (tlo, thi] t-ownership: strict lower via floor+1.
            // Neighbor tiles compute bit-identical boundary values -> each
            // sample counted exactly once.
            float tlo = T0 - 1.0f, thi = -T0;
            const float eps = 1e-7f;
            if (sn > eps) {
                float r = __frcp_rn(sn);
                tlo = fmaxf(tlo, (sx - xhi) * r);
                thi = fminf(thi, (sx - xlo) * r);
            } else if (sx < xlo || sx >= xhi) {
                active = false;
            }
            if (c > eps) {
                float r = __frcp_rn(c);
                tlo = fmaxf(tlo, (ylo - sy) * r);
                thi = fminf(thi, (yhi - sy) * r);
            } else if (c < -eps) {
                float r = __frcp_rn(c);
                tlo = fmaxf(tlo, (yhi - sy) * r);
                thi = fminf(thi, (ylo - sy) * r);
            } else if (sy < ylo || sy >= yhi) {
                active = false;
            }

            float a = fmaxf(fminf(tlo - T0, 726.0f), -2.0f);
            float b = fmaxf(fminf(thi - T0, 724.0f), -3.0f);
            int tt0 = max(0, (int)floorf(a) + 1);
            int tt1 = (int)floorf(b);
            if (!active) tt1 = tt0 - 1;
            int n = tt1 - tt0 + 1;

            float t0f = (float)tt0 + T0;
            float xs = fmaf(t0f, -sn, sx) - x0f + 2.0f;   // local x
            float ys = fmaf(t0f, c, sy) - y0f + 2.0f;     // local y
            v2f pos, stp;
            if (classA) { pos = (v2f){xs, ys}; stp = (v2f){-sn, c}; }
            else        { pos = (v2f){ys, xs}; stp = (v2f){c, -sn}; }

            v2f acc0 = {0.0f, 0.0f}, acc1 = {0.0f, 0.0f};
            v2f acc2 = {0.0f, 0.0f}, acc3 = {0.0f, 0.0f};
            v2f stp4 = (stp + stp) + (stp + stp);
            int k = n;
            while (k >= 4) {
                v2f p1 = pos + stp;
                v2f p2 = p1 + stp;
                v2f p3 = p2 + stp;
                lsamp(lds, pos, acc0);
                lsamp(lds, p1, acc1);
                lsamp(lds, p2, acc2);
                lsamp(lds, p3, acc3);
                pos += stp4;
                k -= 4;
            }
            while (k > 0) {
                lsamp(lds, pos, acc0);
                pos += stp;
                k -= 1;
            }
            v2f acc = (acc0 + acc1) + (acc2 + acc3);

            if (n > 0) {
                atomicAdd(&out[view * NDCT + det], acc.x);
                atomicAdd(&out[NVIEW * NDCT + view * NDCT + det], acc.y);
            }
        };

        do_ray(detlo + (half << 6) + lane);
        // span can slightly exceed 128 dets: rare short overflow pass.
        if (half == 1 && detlo + 128 <= dethi) do_ray(detlo + 128 + lane);
    }
}

extern "C" void kernel_launch(void* const* d_in, const int* in_sizes, int n_in,
                              void* d_out, int out_size, void* d_ws, size_t ws_size,
                              hipStream_t stream) {
    const float* in = (const float*)d_in[0];
    float* out = (float*)d_out;
    __half2* packed = (__half2*)d_ws;            // PW*PH*4  ~1.06 MiB
    __half2* packedT = packed + PW * PH;         // +1.06 MiB

    hipMemsetAsync(d_out, 0, (size_t)out_size * sizeof(float), stream);

    {
        int n = PH * PW;
        int threads = 256;
        int blocks = (n + threads - 1) / threads;
        repack_kernel<<<blocks, threads, 0, stream>>>(in, packed, packedT);
    }
    {
        dim3 block(512, 1, 1);
        dim3 grid(64, NVIEW / VCHUNK, 1);
        radon_tile_kernel<<<grid, block, 0, stream>>>(packed, packedT, out);
    }
}

// Round 15
// 243.494 us; speedup vs baseline: 1.1022x; 1.1022x over previous
//
#include <hip/hip_runtime.h>
#include <hip/hip_fp16.h>

typedef float v2f __attribute__((ext_vector_type(2)));

#define IMG_H 512
#define IMG_W 512
#define NVIEW 768
#define NDCT 736
#define NT 725
#define PAD 2
#define PW (IMG_W + 2 * PAD)   // 516
#define PH (IMG_H + 2 * PAD)   // 516
#define TROWS 20               // minor axis 16 + 4 margin
#define TCOLS 132              // major axis 128 + 4 margin
#define LSTR 160               // LDS row stride in 8B entries (0 mod 16)
#define VCHUNK 16

typedef struct { __half2 a, b; } h2x2;   // 8 B: texel(r,x), texel(r+1,x)

// Repack [2,H,W] float -> zero-padded [PH,PW] __half2 (ch0,ch1), plus
// transposed copy.
__global__ void repack_kernel(const float* __restrict__ in,
                              __half2* __restrict__ packed,
                              __half2* __restrict__ packedT) {
    int i = blockIdx.x * blockDim.x + threadIdx.x;
    if (i < PH * PW) {
        int py = i / PW;
        int px = i - py * PW;
        int y = py - PAD;
        int x = px - PAD;
        float2 v = make_float2(0.0f, 0.0f);
        if ((unsigned)x < (unsigned)IMG_W && (unsigned)y < (unsigned)IMG_H) {
            v = make_float2(in[y * IMG_W + x], in[IMG_H * IMG_W + y * IMG_W + x]);
        }
        __half2 h = __floats2half2_rn(v.x, v.y);
        packed[py * PW + px] = h;      // [y][x]
        packedT[px * PW + py] = h;     // [x][y]
    }
}

// Bilinear sample at pos=(col,row). Row-paired entries: lds[idx] holds rows
// (yi, yi+1) at col xi -> entries idx, idx+1 give all 4 texels x 2 channels.
// Lerp in packed f16, accumulate in f16 (flushed per visit).
__device__ __forceinline__ void lsamp(const h2x2* __restrict__ lds, v2f pos, __half2& acc) {
    float fx = floorf(pos.x);
    float fy = floorf(pos.y);
    int xi = (int)fx;
    int yi = (int)fy;
    float wx = pos.x - fx;
    float wy = pos.y - fy;
    int idx = yi * LSTR + xi;
    h2x2 L = lds[idx];        // a = v00, b = v10
    h2x2 R = lds[idx + 1];    // a = v01, b = v11
    __half2 hwx = __float2half2_rn(wx);
    __half2 hwy = __float2half2_rn(wy);
    __half2 top = __hfma2(hwx, __hsub2(R.a, L.a), L.a);
    __half2 bot = __hfma2(hwx, __hsub2(R.b, L.b), L.b);
    acc = __hadd2(acc, __hfma2(hwy, __hsub2(bot, top), top));
}

__global__ __launch_bounds__(512, 8) void radon_tile_kernel(const __half2* __restrict__ packed,
                                                            const __half2* __restrict__ packedT,
                                                            float* __restrict__ out) {
    __shared__ h2x2 lds[TROWS * LSTR];   // 25600 B

    const int tid = threadIdx.x;
    const int bx = blockIdx.x;
    const int by = blockIdx.y;
    const bool classA = (by < 12) || (by >= 36);   // |cos| >= |sin|

    int x0, y0;
    float xlo, xhi, ylo, yhi;
    if (classA) {                 // tile 128 wide (x) x 16 tall (y)
        int tx = bx & 3, ty = bx >> 2;         // 4 x 32
        x0 = tx * 128; y0 = ty * 16;
        xlo = (tx == 0) ? -1.25f : (float)x0;
        xhi = (tx == 3) ? 512.25f : (float)(x0 + 128);
        ylo = (ty == 0) ? -1.25f : (float)y0;
        yhi = (ty == 31) ? 512.25f : (float)(y0 + 16);
    } else {                      // tile 16 wide (x) x 128 tall (y)
        int tx = bx & 31, ty = bx >> 5;        // 32 x 4
        x0 = tx * 16; y0 = ty * 128;
        xlo = (tx == 0) ? -1.25f : (float)x0;
        xhi = (tx == 31) ? 512.25f : (float)(x0 + 16);
        ylo = (ty == 0) ? -1.25f : (float)y0;
        yhi = (ty == 3) ? 512.25f : (float)(y0 + 128);
    }

    // Stage 20x132 row-paired entries; class B reads the transposed copy.
    {
        const __half2* src = classA ? packed : packedT;
        const int rbase = classA ? y0 : x0;
        const int cbase = classA ? x0 : y0;
        for (int i = tid; i < TROWS * TCOLS; i += 512) {
            int r = i / TCOLS;
            int cc = i - r * TCOLS;
            int gr = rbase + r;
            int gr2 = min(gr + 1, PH - 1);   // row PH-1 is zero-pad; clamp = zeros
            h2x2 e;
            e.a = src[gr * PW + cbase + cc];
            e.b = src[gr2 * PW + cbase + cc];
            lds[r * LSTR + cc] = e;
        }
    }
    __syncthreads();

    const int wid = tid >> 6;
    const int lane = tid & 63;
    const float cx = 255.5f;        // == cy
    const float doff = 367.5f;      // (NDCT-1)/2
    const float T0 = -362.0f;       // -(NT-1)/2
    const float x0f = (float)x0, y0f = (float)y0;
    const int vbase = by * VCHUNK;

    for (int task = wid; task < 2 * VCHUNK; task += 8) {
        const int view = vbase + (task >> 1);
        const int half = task & 1;
        const float theta = (float)view * (float)(3.14159265358979323846 / (double)NVIEW);
        float sn, c;
        sincosf(theta, &sn, &c);

        // det range touching this tile: s = c*(x-cx) + sn*(y-cy).
        float xa = c * (xlo - cx), xb = c * (xhi - cx);
        float ya = sn * (ylo - cx), yb = sn * (yhi - cx);
        float smin = fminf(xa, xb) + fminf(ya, yb) - 1.0f;
        float smax = fmaxf(xa, xb) + fmaxf(ya, yb) + 1.0f;
        int detlo = max(0, (int)ceilf(smin + doff));
        int dethi = min(NDCT - 1, (int)floorf(smax + doff));

        if (detlo + (half << 6) > dethi) continue;

        auto do_ray = [&](int det) {
            bool active = (det <= dethi);
            float s = (float)det - doff;
            float sx = fmaf(s, c, cx);      // x(t) = sx - t*sn
            float sy = fmaf(s, sn, cx);     // y(t) = sy + t*c

            // Half-open (tlo, thi] t-ownership: strict lower via floor+1.
            // Neighbor tiles compute bit-identical boundary values -> each
            // sample counted exactly once.
            float tlo = T0 - 1.0f, thi = -T0;
            const float eps = 1e-7f;
            if (sn > eps) {
                float r = __frcp_rn(sn);
                tlo = fmaxf(tlo, (sx - xhi) * r);
                thi = fminf(thi, (sx - xlo) * r);
            } else if (sx < xlo || sx >= xhi) {
                active = false;
            }
            if (c > eps) {
                float r = __frcp_rn(c);
                tlo = fmaxf(tlo, (ylo - sy) * r);
                thi = fminf(thi, (yhi - sy) * r);
            } else if (c < -eps) {
                float r = __frcp_rn(c);
                tlo = fmaxf(tlo, (yhi - sy) * r);
                thi = fminf(thi, (ylo - sy) * r);
            } else if (sy < ylo || sy >= yhi) {
                active = false;
            }

            float a = fmaxf(fminf(tlo - T0, 726.0f), -2.0f);
            float b = fmaxf(fminf(thi - T0, 724.0f), -3.0f);
            int tt0 = max(0, (int)floorf(a) + 1);
            int tt1 = (int)floorf(b);
            if (!active) tt1 = tt0 - 1;
            int n = tt1 - tt0 + 1;

            float t0f = (float)tt0 + T0;
            float xs = fmaf(t0f, -sn, sx) - x0f + 2.0f;   // local x
            float ys = fmaf(t0f, c, sy) - y0f + 2.0f;     // local y
            v2f pos, stp;
            if (classA) { pos = (v2f){xs, ys}; stp = (v2f){-sn, c}; }
            else        { pos = (v2f){ys, xs}; stp = (v2f){c, -sn}; }

            __half2 hacc0 = __floats2half2_rn(0.0f, 0.0f);
            __half2 hacc1 = __floats2half2_rn(0.0f, 0.0f);
            v2f stp2 = stp + stp;
            int k = n;
            while (k >= 2) {
                v2f p1 = pos + stp;
                lsamp(lds, pos, hacc0);
                lsamp(lds, p1, hacc1);
                pos += stp2;
                k -= 2;
            }
            if (k == 1) lsamp(lds, pos, hacc0);
            __half2 hs = __hadd2(hacc0, hacc1);

            if (n > 0) {
                atomicAdd(&out[view * NDCT + det], __low2float(hs));
                atomicAdd(&out[NVIEW * NDCT + view * NDCT + det], __high2float(hs));
            }
        };

        do_ray(detlo + (half << 6) + lane);
        // span can slightly exceed 128 dets: rare short overflow pass.
        if (half == 1 && detlo + 128 <= dethi) do_ray(detlo + 128 + lane);
    }
}

extern "C" void kernel_launch(void* const* d_in, const int* in_sizes, int n_in,
                              void* d_out, int out_size, void* d_ws, size_t ws_size,
                              hipStream_t stream) {
    const float* in = (const float*)d_in[0];
    float* out = (float*)d_out;
    __half2* packed = (__half2*)d_ws;            // PW*PH*4  ~1.06 MiB
    __half2* packedT = packed + PW * PH;         // +1.06 MiB

    hipMemsetAsync(d_out, 0, (size_t)out_size * sizeof(float), stream);

    {
        int n = PH * PW;
        int threads = 256;
        int blocks = (n + threads - 1) / threads;
        repack_kernel<<<blocks, threads, 0, stream>>>(in, packed, packedT);
    }
    {
        dim3 block(512, 1, 1);
        dim3 grid(128, NVIEW / VCHUNK, 1);
        radon_tile_kernel<<<grid, block, 0, stream>>>(packed, packedT, out);
    }
}